// Round 15
// baseline (59.186 us; speedup 1.0000x reference)
//
#include <hip/hip_runtime.h>
#include <hip/hip_bf16.h>
#include <stdint.h>

// Flash-attention forward: B=16, Lq=Lk=2048, D=64, fp32 in/out, bf16 MFMA.
// Round 15: LPT work-stealing. r14 showed time-avg occupancy ~3/32 waves/CU:
// ~30us of 40 is TAIL (few CUs grind heavy batches, rest idle). Fix: prep
// sorts batches by valid desc -> order[16]; 512 persistent blocks pull 1024
// fine items (b=order[item>>6], qt=item&63, 32 q-rows, full-K) from an atomic
// queue. Heaviest batch's items pulled FIRST (LPT): makespan ~ total/P +
// light tail. Single-Q r11 loop (76 VGPR, no spill), tiled V^T.

#define BATCH 16
#define SEQ   2048
#define DIM   64
#define NSPLIT 4
#define NTHR  256
#define NITEMS 1024

typedef __bf16 bf16x8 __attribute__((ext_vector_type(8)));
typedef float  f32x16 __attribute__((ext_vector_type(16)));
typedef unsigned int u32x2 __attribute__((ext_vector_type(2)));

static constexpr float QSCALE = 0.125f * 1.44269504088896340736f; // 1/sqrt(D)*log2(e)

__device__ __forceinline__ uint32_t pk2bf(float a, float b) {
    union { __hip_bfloat162 h; uint32_t u; } c;
    c.h = __float22bfloat162_rn(make_float2(a, b));
    return c.u;
}
__device__ __forceinline__ bf16x8 mk8(uint32_t w0, uint32_t w1, uint32_t w2, uint32_t w3) {
    union { uint32_t u[4]; bf16x8 v; } c;
    c.u[0] = w0; c.u[1] = w1; c.u[2] = w2; c.u[3] = w3;
    return c.v;
}
__device__ __forceinline__ u32x2 plswap(uint32_t a, uint32_t b) {
    return __builtin_amdgcn_permlane32_swap(a, b, false, false);
}
__device__ __forceinline__ float vmax16(const f32x16& v) {
    float a = fmaxf(fmaxf(v[0], v[1]), fmaxf(v[2], v[3]));
    float b = fmaxf(fmaxf(v[4], v[5]), fmaxf(v[6], v[7]));
    float c = fmaxf(fmaxf(v[8], v[9]), fmaxf(v[10], v[11]));
    float d = fmaxf(fmaxf(v[12], v[13]), fmaxf(v[14], v[15]));
    return fmaxf(fmaxf(a, b), fmaxf(c, d));
}
__device__ __forceinline__ float vsum16(const f32x16& v) {
    float a = (v[0] + v[1]) + (v[2] + v[3]);
    float b = (v[4] + v[5]) + (v[6] + v[7]);
    float c = (v[8] + v[9]) + (v[10] + v[11]);
    float d = (v[12] + v[13]) + (v[14] + v[15]);
    return (a + b) + (c + d);
}

// -------- pre-pass: K -> bf16 [b][k][d]; V -> bf16 tiled V^T [b][t][64][32];
// -------- block 0 also sorts batches by valid desc + zeroes the counter ----
__global__ __launch_bounds__(256) void prep_kv(
        const float* __restrict__ K, const float* __restrict__ V,
        const int* __restrict__ VL,
        unsigned short* __restrict__ Kbf, unsigned short* __restrict__ Vt,
        unsigned int* __restrict__ counter, int* __restrict__ order)
{
    __shared__ float tl[64][65];          // +1 pad: conflict-free column reads
    const int bid = blockIdx.x;           // 512 = 16 b x 32 k-blocks of 64
    const int b  = bid >> 5;
    const int kb = (bid & 31) * 64;
    const int tid = threadIdx.x;

    if (bid == 0 && tid == 0) {
        *counter = 0u;
        int idxs[BATCH], vals[BATCH];
        #pragma unroll
        for (int i = 0; i < BATCH; ++i) { idxs[i] = i; vals[i] = VL[i]; }
        // stable insertion sort, descending by valid
        for (int i = 1; i < BATCH; ++i) {
            int vi = vals[i], xi = idxs[i], j = i - 1;
            while (j >= 0 && vals[j] < vi) {
                vals[j + 1] = vals[j]; idxs[j + 1] = idxs[j]; --j;
            }
            vals[j + 1] = vi; idxs[j + 1] = xi;
        }
        #pragma unroll
        for (int i = 0; i < BATCH; ++i) order[i] = idxs[i];
    }

    const float* Kp = K + ((size_t)b * SEQ + kb) * DIM;
    const float* Vp = V + ((size_t)b * SEQ + kb) * DIM;
    unsigned short* Ko = Kbf + ((size_t)b * SEQ + kb) * DIM;
    unsigned short* Vo = Vt + (size_t)b * SEQ * DIM + (size_t)(kb >> 5) * 2048;

    #pragma unroll
    for (int p = 0; p < 4; ++p) {         // K: straight convert, coalesced
        int idx = p * 256 + tid;          // 0..1023 quads
        float4 x = ((const float4*)Kp)[idx];
        ((uint2*)Ko)[idx] = make_uint2(pk2bf(x.x, x.y), pk2bf(x.z, x.w));
    }
    #pragma unroll
    for (int p = 0; p < 4; ++p) {         // V tile -> LDS
        int idx = p * 256 + tid;
        int r = idx >> 4, c = (idx & 15) * 4;
        float4 x = *(const float4*)(Vp + r * DIM + c);
        tl[r][c] = x.x; tl[r][c+1] = x.y; tl[r][c+2] = x.z; tl[r][c+3] = x.w;
    }
    __syncthreads();
    #pragma unroll
    for (int p = 0; p < 4; ++p) {         // transposed tiled store, coalesced
        int idx = p * 256 + tid;          // 0..1023
        int sub = idx >> 9;               // 32-key subtile 0..1
        int rem = idx & 511;
        int d  = rem >> 3;                // 0..63
        int kq = (rem & 7) * 4;           // 0..28
        int kr = sub * 32 + kq;           // key row in tl
        *(uint2*)(Vo + sub * 2048 + d * 32 + kq) =
            make_uint2(pk2bf(tl[kr][d],     tl[kr + 1][d]),
                       pk2bf(tl[kr + 2][d], tl[kr + 3][d]));
    }
}

// ---------------- main: work-stealing register-streaming flash attention ---
__global__ __launch_bounds__(NTHR, 2) void attn_main(
        const float* __restrict__ Q, const unsigned short* __restrict__ Kbf,
        const unsigned short* __restrict__ Vt, const int* __restrict__ VL,
        float* __restrict__ O, unsigned int* __restrict__ counter,
        const int* __restrict__ order)
{
    __shared__ float comb[NSPLIT - 1][2176];   // 32x64 O^T + m + l per writer
    __shared__ int item_s;

    const int tid  = threadIdx.x;
    const int split = tid >> 6;           // wave 0..3 = KV split
    const int lane = tid & 63;
    const int h    = lane >> 5;
    const int ln   = lane & 31;

    for (;;) {
        if (tid == 0) item_s = (int)atomicAdd(counter, 1u);
        __syncthreads();
        const int item = item_s;
        if (item >= NITEMS) break;

        // LPT order: items of the heaviest batch first (contiguous run).
        const int b  = order[item >> 6];
        const int qt = item & 63;         // 32-row q-tile
        const int valid  = VL[b];
        const int ntiles = (valid + 31) >> 5;
        const size_t bOff = (size_t)b * SEQ * DIM;
        const int qrow = qt * 32 + ln;

        // ---- Q fragments (B-operand of S^T = K * Q^T), scaled ----
        bf16x8 qf[4];
        {
            const float* qp = Q + bOff + (size_t)qrow * DIM;
            #pragma unroll
            for (int s = 0; s < 4; ++s) {
                int c0 = s * 16 + h * 8;
                float4 x = *(const float4*)(qp + c0);
                float4 y = *(const float4*)(qp + c0 + 4);
                qf[s] = mk8(pk2bf(x.x * QSCALE, x.y * QSCALE),
                            pk2bf(x.z * QSCALE, x.w * QSCALE),
                            pk2bf(y.x * QSCALE, y.y * QSCALE),
                            pk2bf(y.z * QSCALE, y.w * QSCALE));
            }
        }

        f32x16 o0, o1;
        #pragma unroll
        for (int r = 0; r < 16; ++r) { o0[r] = 0.0f; o1[r] = 0.0f; }
        float m_run = -1e30f, l_run = 0.0f;

        const unsigned short* kp = Kbf + bOff + (size_t)ln * DIM + h * 8;
        const unsigned short* vp = Vt  + bOff + (size_t)ln * 32  + h * 8;

        bf16x8 ka[4], va[4];
        int kt = split;
        if (kt < ntiles) {
            const unsigned short* kq = kp + (size_t)kt * 2048;
            const unsigned short* vq = vp + (size_t)kt * 2048;
            #pragma unroll
            for (int s = 0; s < 4; ++s) ka[s] = *(const bf16x8*)(kq + s * 16);
            va[0] = *(const bf16x8*)(vq);
            va[1] = *(const bf16x8*)(vq + 16);
            va[2] = *(const bf16x8*)(vq + 1024);
            va[3] = *(const bf16x8*)(vq + 1024 + 16);
        }

        for (; kt < ntiles; kt += NSPLIT) {
            // ---- prefetch next tile's K/V a full iteration ahead ----
            const int ktn = (kt + NSPLIT < ntiles) ? kt + NSPLIT : kt;
            bf16x8 kan[4], van[4];
            {
                const unsigned short* kq = kp + (size_t)ktn * 2048;
                const unsigned short* vq = vp + (size_t)ktn * 2048;
                #pragma unroll
                for (int s = 0; s < 4; ++s) kan[s] = *(const bf16x8*)(kq + s * 16);
                van[0] = *(const bf16x8*)(vq);
                van[1] = *(const bf16x8*)(vq + 16);
                van[2] = *(const bf16x8*)(vq + 1024);
                van[3] = *(const bf16x8*)(vq + 1024 + 16);
            }

            // ---- S^T = K * Q^T (32k x 32q) ----
            f32x16 st;
            #pragma unroll
            for (int r = 0; r < 16; ++r) st[r] = 0.0f;
            #pragma unroll
            for (int s = 0; s < 4; ++s)
                st = __builtin_amdgcn_mfma_f32_32x32x16_bf16(ka[s], qf[s], st, 0, 0, 0);

            // ---- mask tail (reproduces -1e6 fill: weight 0) ----
            const int kb = kt * 32;
            if (kb + 32 > valid) {
                #pragma unroll
                for (int r = 0; r < 16; ++r) {
                    int krel = (r & 3) + 8 * (r >> 2) + 4 * h;
                    if (kb + krel >= valid) st[r] = -1e30f;
                }
            }

            // ---- online softmax, defer-max (T13, THR=8 in log2 units) ----
            float pm = vmax16(st);
            u32x2 sm = plswap(__float_as_uint(pm), __float_as_uint(pm));
            pm = fmaxf(__uint_as_float(sm[0]), __uint_as_float(sm[1]));
            if (!__all(pm <= m_run + 8.0f)) {
                float mnew = fmaxf(m_run, pm);
                float sc = __builtin_exp2f(m_run - mnew);
                l_run *= sc;
                #pragma unroll
                for (int r = 0; r < 16; ++r) { o0[r] *= sc; o1[r] *= sc; }
                m_run = mnew;
            }
            #pragma unroll
            for (int r = 0; r < 16; ++r) st[r] = __builtin_exp2f(st[r] - m_run);
            float ps = vsum16(st);
            u32x2 ss = plswap(__float_as_uint(ps), __float_as_uint(ps));
            l_run += __uint_as_float(ss[0]) + __uint_as_float(ss[1]);

            // ---- P^T -> bf16 B-fragments (cvt_pk + permlane32_swap) ----
            uint32_t W00 = pk2bf(st[0],  st[1]),  W01 = pk2bf(st[2],  st[3]);
            uint32_t W10 = pk2bf(st[4],  st[5]),  W11 = pk2bf(st[6],  st[7]);
            uint32_t W20 = pk2bf(st[8],  st[9]),  W21 = pk2bf(st[10], st[11]);
            uint32_t W30 = pk2bf(st[12], st[13]), W31 = pk2bf(st[14], st[15]);
            u32x2 sA = plswap(W00, W10), sB = plswap(W01, W11);
            bf16x8 bp0 = mk8(sA[0], sB[0], sA[1], sB[1]);
            u32x2 sC = plswap(W20, W30), sD = plswap(W21, W31);
            bf16x8 bp1 = mk8(sC[0], sD[0], sC[1], sD[1]);

            // ---- O^T += V^T * P^T ----
            o0 = __builtin_amdgcn_mfma_f32_32x32x16_bf16(va[0], bp0, o0, 0, 0, 0);
            o1 = __builtin_amdgcn_mfma_f32_32x32x16_bf16(va[2], bp0, o1, 0, 0, 0);
            o0 = __builtin_amdgcn_mfma_f32_32x32x16_bf16(va[1], bp1, o0, 0, 0, 0);
            o1 = __builtin_amdgcn_mfma_f32_32x32x16_bf16(va[3], bp1, o1, 0, 0, 0);

            #pragma unroll
            for (int i = 0; i < 4; ++i) { ka[i] = kan[i]; va[i] = van[i]; }
        }

        // ---- 4-way split merge through LDS ----
        if (split != 0) {
            float* base = comb[split - 1];
            #pragma unroll
            for (int r = 0; r < 16; ++r) {
                base[r * 64 + lane]        = o0[r];
                base[(r + 16) * 64 + lane] = o1[r];
            }
            base[2048 + lane]      = m_run;
            base[2048 + 64 + lane] = l_run;
        }
        __syncthreads();
        if (split == 0) {
            float M = m_run;
            #pragma unroll
            for (int j = 0; j < NSPLIT - 1; ++j)
                M = fmaxf(M, comb[j][2048 + lane]);
            float sc0 = __builtin_exp2f(m_run - M);
            float lt = l_run * sc0;
            #pragma unroll
            for (int r = 0; r < 16; ++r) { o0[r] *= sc0; o1[r] *= sc0; }
            #pragma unroll
            for (int j = 0; j < NSPLIT - 1; ++j) {
                float mj = comb[j][2048 + lane];
                float lj = comb[j][2048 + 64 + lane];
                float scj = __builtin_exp2f(mj - M);
                lt += lj * scj;
                #pragma unroll
                for (int r = 0; r < 16; ++r) {
                    o0[r] += scj * comb[j][r * 64 + lane];
                    o1[r] += scj * comb[j][(r + 16) * 64 + lane];
                }
            }
            float inv = 1.0f / lt;
            float* op = O + bOff + (size_t)qrow * DIM;
            #pragma unroll
            for (int a = 0; a < 4; ++a) {
                float4 w0, w1;
                w0.x = o0[4*a+0] * inv; w0.y = o0[4*a+1] * inv;
                w0.z = o0[4*a+2] * inv; w0.w = o0[4*a+3] * inv;
                w1.x = o1[4*a+0] * inv; w1.y = o1[4*a+1] * inv;
                w1.z = o1[4*a+2] * inv; w1.w = o1[4*a+3] * inv;
                *(float4*)(op + 8*a + 4*h)      = w0;   // d = (r&3)+8*(r>>2)+4h
                *(float4*)(op + 32 + 8*a + 4*h) = w1;   // tile1: +32
            }
        }
        __syncthreads();   // comb consumed + item_s reusable
    }
}

// ---------------- fallback (round-3 LDS kernel) if ws too small ------------
__device__ __forceinline__ uint32_t swz(uint32_t row, uint32_t colByte) {
    return row * 128u + (colByte ^ ((row & 7u) << 4));
}
__device__ __forceinline__ bf16x8 lds8(const char* p) {
    union { uint4 q; bf16x8 v; } c;
    c.q = *(const uint4*)p;
    return c.v;
}

__global__ __launch_bounds__(256, 2) void attn_fallback(
        const float* __restrict__ Q, const float* __restrict__ K,
        const float* __restrict__ V, const int* __restrict__ VL,
        float* __restrict__ O)
{
    __shared__ unsigned short lds[2][2][64 * DIM];
    const int tid  = threadIdx.x;
    const int bid  = blockIdx.x;
    const int b    = bid & (BATCH - 1);
    const int qt   = bid >> 4;
    const int qb   = qt * 64;
    const int qhalf = (tid >> 6) & 1;
    const int split = tid >> 7;
    const int lane = tid & 63;
    const int h    = lane >> 5;
    const int ln   = lane & 31;
    const int ptid = tid & 127;

    const int valid  = VL[b];
    const int ntiles = (valid + 63) / 64;
    const int nit    = (ntiles + 1) / 2;

    const size_t bOff = (size_t)b * SEQ * DIM;
    const int qrow = qb + qhalf * 32 + ln;

    bf16x8 qf[4];
    {
        const float* qp = Q + bOff + (size_t)qrow * DIM;
        #pragma unroll
        for (int s = 0; s < 4; ++s) {
            int c0 = s * 16 + h * 8;
            float4 x = *(const float4*)(qp + c0);
            float4 y = *(const float4*)(qp + c0 + 4);
            qf[s] = mk8(pk2bf(x.x * QSCALE, x.y * QSCALE),
                        pk2bf(x.z * QSCALE, x.w * QSCALE),
                        pk2bf(y.x * QSCALE, y.y * QSCALE),
                        pk2bf(y.z * QSCALE, y.w * QSCALE));
        }
    }
    f32x16 o0, o1;
    #pragma unroll
    for (int r = 0; r < 16; ++r) { o0[r] = 0.0f; o1[r] = 0.0f; }
    float m_run = -1e30f, l_run = 0.0f;
    const float* Kb = K + bOff;
    const float* Vb = V + bOff;
    char* kls = (char*)lds[split][0];
    char* vls = (char*)lds[split][1];

    for (int it = 0; it < nit; ++it) {
        const int kt = it * 2 + split;
        const bool act = kt < ntiles;
        const int kb = kt * 64;
        if (act) {
            #pragma unroll
            for (int p = 0; p < 8; ++p) {
                int idx = p * 128 + ptid;
                int r = idx >> 4, c = (idx & 15) * 4;
                float4 kx = *(const float4*)(Kb + (size_t)(kb + r) * DIM + c);
                *(uint2*)(kls + swz(r, c * 2)) =
                    make_uint2(pk2bf(kx.x, kx.y), pk2bf(kx.z, kx.w));
            }
            #pragma unroll
            for (int p = 0; p < 2; ++p) {
                int idx = p * 128 + ptid;
                int cq = idx & 15, rq = idx >> 4;
                const float* vp = Vb + (size_t)(kb + rq * 4) * DIM + cq * 4;
                float4 v0 = *(const float4*)(vp);
                float4 v1 = *(const float4*)(vp + DIM);
                float4 v2 = *(const float4*)(vp + 2 * DIM);
                float4 v3 = *(const float4*)(vp + 3 * DIM);
                float a0[4] = {v0.x, v0.y, v0.z, v0.w};
                float a1[4] = {v1.x, v1.y, v1.z, v1.w};
                float a2[4] = {v2.x, v2.y, v2.z, v2.w};
                float a3[4] = {v3.x, v3.y, v3.z, v3.w};
                #pragma unroll
                for (int i = 0; i < 4; ++i)
                    *(uint2*)(vls + swz(cq * 4 + i, rq * 8)) =
                        make_uint2(pk2bf(a0[i], a1[i]), pk2bf(a2[i], a3[i]));
            }
        }
        __syncthreads();
        if (act) {
            f32x16 st0, st1;
            #pragma unroll
            for (int r = 0; r < 16; ++r) { st0[r] = 0.0f; st1[r] = 0.0f; }
            #pragma unroll
            for (int s = 0; s < 4; ++s) {
                int cb = (s * 16 + h * 8) * 2;
                bf16x8 ka0 = lds8(kls + swz(ln,      cb));
                bf16x8 ka1 = lds8(kls + swz(ln + 32, cb));
                st0 = __builtin_amdgcn_mfma_f32_32x32x16_bf16(ka0, qf[s], st0, 0, 0, 0);
                st1 = __builtin_amdgcn_mfma_f32_32x32x16_bf16(ka1, qf[s], st1, 0, 0, 0);
            }
            if (kb + 64 > valid) {
                #pragma unroll
                for (int r = 0; r < 16; ++r) {
                    int krel = (r & 3) + 8 * (r >> 2) + 4 * h;
                    if (kb + krel      >= valid) st0[r] = -1e30f;
                    if (kb + 32 + krel >= valid) st1[r] = -1e30f;
                }
            }
            float pm = fmaxf(vmax16(st0), vmax16(st1));
            u32x2 sm = plswap(__float_as_uint(pm), __float_as_uint(pm));
            pm = fmaxf(__uint_as_float(sm[0]), __uint_as_float(sm[1]));
            float mnew = fmaxf(m_run, pm);
            float sc = __builtin_exp2f(m_run - mnew);
            #pragma unroll
            for (int r = 0; r < 16; ++r) {
                st0[r] = __builtin_exp2f(st0[r] - mnew);
                st1[r] = __builtin_exp2f(st1[r] - mnew);
            }
            float ps = vsum16(st0) + vsum16(st1);
            u32x2 ss = plswap(__float_as_uint(ps), __float_as_uint(ps));
            ps = __uint_as_float(ss[0]) + __uint_as_float(ss[1]);
            l_run = l_run * sc + ps;
            m_run = mnew;
            #pragma unroll
            for (int r = 0; r < 16; ++r) { o0[r] *= sc; o1[r] *= sc; }
            bf16x8 bp[4];
            {
                uint32_t u0 = pk2bf(st0[0], st0[1]),  u1 = pk2bf(st0[2], st0[3]);
                uint32_t u2 = pk2bf(st0[4], st0[5]),  u3 = pk2bf(st0[6], st0[7]);
                uint32_t u4 = pk2bf(st0[8], st0[9]),  u5 = pk2bf(st0[10], st0[11]);
                uint32_t u6 = pk2bf(st0[12], st0[13]), u7 = pk2bf(st0[14], st0[15]);
                u32x2 s02 = plswap(u0, u2), s13 = plswap(u1, u3);
                bp[0] = mk8(s02[0], s13[0], s02[1], s13[1]);
                u32x2 s46 = plswap(u4, u6), s57 = plswap(u5, u7);
                bp[1] = mk8(s46[0], s57[0], s46[1], s57[1]);
            }
            {
                uint32_t u0 = pk2bf(st1[0], st1[1]),  u1 = pk2bf(st1[2], st1[3]);
                uint32_t u2 = pk2bf(st1[4], st1[5]),  u3 = pk2bf(st1[6], st1[7]);
                uint32_t u4 = pk2bf(st1[8], st1[9]),  u5 = pk2bf(st1[10], st1[11]);
                uint32_t u6 = pk2bf(st1[12], st1[13]), u7 = pk2bf(st1[14], st1[15]);
                u32x2 s02 = plswap(u0, u2), s13 = plswap(u1, u3);
                bp[2] = mk8(s02[0], s13[0], s02[1], s13[1]);
                u32x2 s46 = plswap(u4, u6), s57 = plswap(u5, u7);
                bp[3] = mk8(s46[0], s57[0], s46[1], s57[1]);
            }
            #pragma unroll
            for (int x = 0; x < 4; ++x) {
                int cb = (x * 16 + h * 8) * 2;
                bf16x8 va0 = lds8(vls + swz(ln,      cb));
                bf16x8 va1 = lds8(vls + swz(ln + 32, cb));
                o0 = __builtin_amdgcn_mfma_f32_32x32x16_bf16(va0, bp[x], o0, 0, 0, 0);
                o1 = __builtin_amdgcn_mfma_f32_32x32x16_bf16(va1, bp[x], o1, 0, 0, 0);
            }
        }
        __syncthreads();
    }
    const int CSTRIDE = 32 * 64 + 128;
    float* comb = (float*)lds;
    if (split != 0) {
        float* base = comb + (size_t)qhalf * CSTRIDE;
        #pragma unroll
        for (int r = 0; r < 16; ++r) {
            base[r * 64 + lane]        = o0[r];
            base[(r + 16) * 64 + lane] = o1[r];
        }
        base[2048 + lane]      = m_run;
        base[2048 + 64 + lane] = l_run;
    }
    __syncthreads();
    if (split == 0) {
        float* base = comb + (size_t)qhalf * CSTRIDE;
        float mj = base[2048 + lane];
        float lj = base[2048 + 64 + lane];
        float M  = fmaxf(m_run, mj);
        float sc0 = __builtin_exp2f(m_run - M);
        float scj = __builtin_exp2f(mj - M);
        float lt = l_run * sc0 + lj * scj;
        float inv = 1.0f / lt;
        float* op = O + bOff + (size_t)qrow * DIM;
        #pragma unroll
        for (int a = 0; a < 4; ++a) {
            float4 w0, w1;
            w0.x = (o0[4*a+0]*sc0 + scj*base[(4*a+0)*64 + lane]) * inv;
            w0.y = (o0[4*a+1]*sc0 + scj*base[(4*a+1)*64 + lane]) * inv;
            w0.z = (o0[4*a+2]*sc0 + scj*base[(4*a+2)*64 + lane]) * inv;
            w0.w = (o0[4*a+3]*sc0 + scj*base[(4*a+3)*64 + lane]) * inv;
            w1.x = (o1[4*a+0]*sc0 + scj*base[(4*a+16)*64 + lane]) * inv;
            w1.y = (o1[4*a+1]*sc0 + scj*base[(4*a+17)*64 + lane]) * inv;
            w1.z = (o1[4*a+2]*sc0 + scj*base[(4*a+18)*64 + lane]) * inv;
            w1.w = (o1[4*a+3]*sc0 + scj*base[(4*a+19)*64 + lane]) * inv;
            *(float4*)(op + 8*a + 4*h)      = w0;
            *(float4*)(op + 32 + 8*a + 4*h) = w1;
        }
    }
}

extern "C" void kernel_launch(void* const* d_in, const int* in_sizes, int n_in,
                              void* d_out, int out_size, void* d_ws, size_t ws_size,
                              hipStream_t stream) {
    const float* q  = (const float*)d_in[0];
    const float* k  = (const float*)d_in[1];
    const float* v  = (const float*)d_in[2];
    const int*   vl = (const int*)d_in[3];
    float* out = (float*)d_out;

    const size_t KBYTES = (size_t)BATCH * SEQ * DIM * 2;   // 4 MB each
    if (ws_size >= 2 * KBYTES + 256) {
        unsigned short* kbf = (unsigned short*)d_ws;
        unsigned short* vt  = (unsigned short*)((char*)d_ws + KBYTES);
        unsigned int* counter = (unsigned int*)((char*)d_ws + 2 * KBYTES);
        int* order = (int*)((char*)d_ws + 2 * KBYTES + 64);
        hipLaunchKernelGGL(prep_kv, dim3(BATCH * (SEQ / 64)), dim3(256), 0, stream,
                           k, v, vl, kbf, vt, counter, order);
        hipLaunchKernelGGL(attn_main, dim3(512), dim3(NTHR), 0, stream,
                           q, kbf, vt, vl, out, counter, order);
    } else {
        hipLaunchKernelGGL(attn_fallback, dim3(BATCH * (SEQ / 64)), dim3(256), 0, stream,
                           q, k, v, vl, out);
    }
}

// Round 16
// 41.726 us; speedup vs baseline: 1.4184x; 1.4184x over previous
//
#include <hip/hip_runtime.h>
#include <hip/hip_bf16.h>
#include <stdint.h>

// Flash-attention forward: B=16, Lq=Lk=2048, D=64, fp32 in/out, bf16 MFMA.
// Round 16: r9 kernel (2 Q-tiles/wave ILP, 512 blocks, 4-way KV split,
// bijective map) with FRAGMENT-MAJOR ws layout. Old layouts made every
// K-fragment load a 32-cache-line transaction (16B/lane at 128B stride) and
// V a 16-line one -> ~192 TA line-lookups/iter/wave, saturating the texture
// address unit (why NO scheduling change r10-r15 helped). New layout stores
// each 32-key tile as [frag][lane][16B]: loads are 64x16B consecutive =
// 8 lines (minimum). Same values, same arithmetic, same absmax.

#define BATCH 16
#define SEQ   2048
#define DIM   64
#define NSPLIT 4
#define NTHR  256

typedef __bf16 bf16x8 __attribute__((ext_vector_type(8)));
typedef float  f32x16 __attribute__((ext_vector_type(16)));
typedef unsigned int u32x2 __attribute__((ext_vector_type(2)));

static constexpr float QSCALE = 0.125f * 1.44269504088896340736f; // 1/sqrt(D)*log2(e)

__device__ __forceinline__ uint32_t pk2bf(float a, float b) {
    union { __hip_bfloat162 h; uint32_t u; } c;
    c.h = __float22bfloat162_rn(make_float2(a, b));
    return c.u;
}
__device__ __forceinline__ bf16x8 mk8(uint32_t w0, uint32_t w1, uint32_t w2, uint32_t w3) {
    union { uint32_t u[4]; bf16x8 v; } c;
    c.u[0] = w0; c.u[1] = w1; c.u[2] = w2; c.u[3] = w3;
    return c.v;
}
__device__ __forceinline__ u32x2 plswap(uint32_t a, uint32_t b) {
    return __builtin_amdgcn_permlane32_swap(a, b, false, false);
}
__device__ __forceinline__ float vmax16(const f32x16& v) {
    float a = fmaxf(fmaxf(v[0], v[1]), fmaxf(v[2], v[3]));
    float b = fmaxf(fmaxf(v[4], v[5]), fmaxf(v[6], v[7]));
    float c = fmaxf(fmaxf(v[8], v[9]), fmaxf(v[10], v[11]));
    float d = fmaxf(fmaxf(v[12], v[13]), fmaxf(v[14], v[15]));
    return fmaxf(fmaxf(a, b), fmaxf(c, d));
}
__device__ __forceinline__ float vsum16(const f32x16& v) {
    float a = (v[0] + v[1]) + (v[2] + v[3]);
    float b = (v[4] + v[5]) + (v[6] + v[7]);
    float c = (v[8] + v[9]) + (v[10] + v[11]);
    float d = (v[12] + v[13]) + (v[14] + v[15]);
    return (a + b) + (c + d);
}

// -------- pre-pass: K,V -> bf16 fragment-major tiles -----------------------
// Per 32-key tile t (4KB): byte offset = t*4096 + frag*1024 + lane*16 + e*2.
// K: frag s, lane = h*32 + r    holds K[row r][d = s*16 + h*8 + e], e=0..7.
// V: frag f, lane = hh*32 + ln  holds V^T[d = (f>>1)*32+ln][kk = (f&1)*16+hh*8+e].
__global__ __launch_bounds__(256) void prep_kv(
        const float* __restrict__ K, const float* __restrict__ V,
        unsigned short* __restrict__ Kws, unsigned short* __restrict__ Vws)
{
    __shared__ float tl[64][65];          // +1 pad: conflict-free column reads
    const int bid = blockIdx.x;           // 512 = 16 b x 32 k-blocks of 64
    const int b  = bid >> 5;
    const int kb = (bid & 31) * 64;
    const int tid = threadIdx.x;

    const float* Kp = K + ((size_t)b * SEQ + kb) * DIM;
    const float* Vp = V + ((size_t)b * SEQ + kb) * DIM;
    // per-batch tile region: 64 tiles x 4096B = 256KB = SEQ*DIM*2 bytes
    char* Ko = (char*)Kws + ((size_t)b * SEQ + kb) * DIM * 2;
    char* Vo = (char*)Vws + ((size_t)b * SEQ + kb) * DIM * 2;

    // ---- K tile -> LDS ----
    #pragma unroll
    for (int p = 0; p < 4; ++p) {
        int idx = p * 256 + tid;          // 0..1023
        int r = idx >> 4, c = (idx & 15) * 4;
        float4 x = *(const float4*)(Kp + r * DIM + c);
        tl[r][c] = x.x; tl[r][c+1] = x.y; tl[r][c+2] = x.z; tl[r][c+3] = x.w;
    }
    __syncthreads();
    // ---- K out: fragment-major, fully coalesced uint2 writes ----
    #pragma unroll
    for (int p = 0; p < 4; ++p) {
        int idx = p * 256 + tid;          // 0..1023 uint2 slots (8KB)
        int o   = idx * 8;                // byte offset in 2-tile block
        int sub = o >> 12;                // tile within 64-key block
        int rem = o & 4095;
        int s   = rem >> 10;
        int li  = (rem >> 4) & 63;        // lane
        int h   = li >> 5, r = li & 31;
        int e0  = (rem & 15) >> 1;        // 0 or 4
        int d0  = s * 16 + h * 8 + e0;
        int R   = sub * 32 + r;
        *(uint2*)(Ko + o) = make_uint2(pk2bf(tl[R][d0],     tl[R][d0 + 1]),
                                       pk2bf(tl[R][d0 + 2], tl[R][d0 + 3]));
    }
    __syncthreads();
    // ---- V tile -> LDS ----
    #pragma unroll
    for (int p = 0; p < 4; ++p) {
        int idx = p * 256 + tid;
        int r = idx >> 4, c = (idx & 15) * 4;
        float4 x = *(const float4*)(Vp + r * DIM + c);
        tl[r][c] = x.x; tl[r][c+1] = x.y; tl[r][c+2] = x.z; tl[r][c+3] = x.w;
    }
    __syncthreads();
    // ---- V out: fragment-major (transposed), coalesced; column gathers
    // from tl are conflict-free thanks to the +1 pad ----
    #pragma unroll
    for (int p = 0; p < 4; ++p) {
        int idx = p * 256 + tid;
        int o   = idx * 8;
        int sub = o >> 12;
        int rem = o & 4095;
        int f   = rem >> 10;
        int li  = (rem >> 4) & 63;
        int hh  = li >> 5, ln = li & 31;
        int e0  = (rem & 15) >> 1;        // 0 or 4
        int kk0 = (f & 1) * 16 + hh * 8 + e0;
        int d   = (f >> 1) * 32 + ln;
        int K0  = sub * 32 + kk0;
        *(uint2*)(Vo + o) = make_uint2(pk2bf(tl[K0][d],     tl[K0 + 1][d]),
                                       pk2bf(tl[K0 + 2][d], tl[K0 + 3][d]));
    }
}

// ---------------- main: register-streaming flash attention ----------------
__global__ __launch_bounds__(NTHR, 2) void attn_main(
        const float* __restrict__ Q, const unsigned short* __restrict__ Kws,
        const unsigned short* __restrict__ Vws, const int* __restrict__ VL,
        float* __restrict__ O)
{
    // per writer (split 1..3): 64 o-regs x 64 lanes + mA,lA,mB,lB
    __shared__ float comb[NSPLIT - 1][64 * 64 + 256];

    const int tid  = threadIdx.x;
    const int idx  = blockIdx.x;
    // bijective: consecutive bids -> different batch (XCD spread); a CU's two
    // resident blocks (bid, bid+256) -> different batches.
    const int b    = ((idx & 15) + (idx >> 8)) & (BATCH - 1);
    const int qt   = (idx >> 4) & 31;     // 0..31
    const int qb   = qt * 64;
    const int split = tid >> 6;           // wave 0..3 = KV split
    const int lane = tid & 63;
    const int h    = lane >> 5;
    const int ln   = lane & 31;

    const int valid  = VL[b];
    const int ntiles = (valid + 31) >> 5;

    const size_t bOff = (size_t)b * SEQ * DIM;

    // ---- Q fragments: two tiles per wave (q-rows qb+ln and qb+32+ln) ----
    bf16x8 qfA[4], qfB[4];
    {
        const float* qpA = Q + bOff + (size_t)(qb + ln) * DIM;
        const float* qpB = Q + bOff + (size_t)(qb + 32 + ln) * DIM;
        #pragma unroll
        for (int s = 0; s < 4; ++s) {
            int c0 = s * 16 + h * 8;
            float4 xa = *(const float4*)(qpA + c0);
            float4 ya = *(const float4*)(qpA + c0 + 4);
            qfA[s] = mk8(pk2bf(xa.x * QSCALE, xa.y * QSCALE),
                         pk2bf(xa.z * QSCALE, xa.w * QSCALE),
                         pk2bf(ya.x * QSCALE, ya.y * QSCALE),
                         pk2bf(ya.z * QSCALE, ya.w * QSCALE));
            float4 xb = *(const float4*)(qpB + c0);
            float4 yb = *(const float4*)(qpB + c0 + 4);
            qfB[s] = mk8(pk2bf(xb.x * QSCALE, xb.y * QSCALE),
                         pk2bf(xb.z * QSCALE, xb.w * QSCALE),
                         pk2bf(yb.x * QSCALE, yb.y * QSCALE),
                         pk2bf(yb.z * QSCALE, yb.w * QSCALE));
        }
    }

    f32x16 oA0, oA1, oB0, oB1;
    #pragma unroll
    for (int r = 0; r < 16; ++r) { oA0[r] = 0.0f; oA1[r] = 0.0f; oB0[r] = 0.0f; oB1[r] = 0.0f; }
    float mA = -1e30f, lA = 0.0f, mB = -1e30f, lB = 0.0f;

    // fragment-major bases: +lane*16 bytes, tiles at t*4096, frags at +1024
    const char* kgl = (const char*)Kws + bOff * 2 + (size_t)lane * 16;
    const char* vgl = (const char*)Vws + bOff * 2 + (size_t)lane * 16;

    bf16x8 ka[4], va[4];
    int kt = split;
    if (kt < ntiles) {
        const char* kq = kgl + (size_t)kt * 4096;
        const char* vq = vgl + (size_t)kt * 4096;
        #pragma unroll
        for (int s = 0; s < 4; ++s) {
            ka[s] = *(const bf16x8*)(kq + s * 1024);
            va[s] = *(const bf16x8*)(vq + s * 1024);
        }
    }

    for (; kt < ntiles; kt += NSPLIT) {
        // ---- prefetch next tile's K/V a full iteration ahead ----
        const int ktn = (kt + NSPLIT < ntiles) ? kt + NSPLIT : kt;
        bf16x8 kan[4], van[4];
        {
            const char* kq = kgl + (size_t)ktn * 4096;
            const char* vq = vgl + (size_t)ktn * 4096;
            #pragma unroll
            for (int s = 0; s < 4; ++s) {
                kan[s] = *(const bf16x8*)(kq + s * 1024);
                van[s] = *(const bf16x8*)(vq + s * 1024);
            }
        }

        // ---- S^T = K * Q^T: two INDEPENDENT chains sharing ka ----
        f32x16 stA, stB;
        #pragma unroll
        for (int r = 0; r < 16; ++r) { stA[r] = 0.0f; stB[r] = 0.0f; }
        #pragma unroll
        for (int s = 0; s < 4; ++s) {
            stA = __builtin_amdgcn_mfma_f32_32x32x16_bf16(ka[s], qfA[s], stA, 0, 0, 0);
            stB = __builtin_amdgcn_mfma_f32_32x32x16_bf16(ka[s], qfB[s], stB, 0, 0, 0);
        }

        // ---- mask tail (reproduces -1e6 fill: weight 0) ----
        const int kb = kt * 32;
        if (kb + 32 > valid) {
            #pragma unroll
            for (int r = 0; r < 16; ++r) {
                int krel = (r & 3) + 8 * (r >> 2) + 4 * h;
                if (kb + krel >= valid) { stA[r] = -1e30f; stB[r] = -1e30f; }
            }
        }

        // ---- online softmax, two independent chains, defer-max THR=8 ----
        float pmA = vmax16(stA);
        float pmB = vmax16(stB);
        u32x2 smA = plswap(__float_as_uint(pmA), __float_as_uint(pmA));
        u32x2 smB = plswap(__float_as_uint(pmB), __float_as_uint(pmB));
        pmA = fmaxf(__uint_as_float(smA[0]), __uint_as_float(smA[1]));
        pmB = fmaxf(__uint_as_float(smB[0]), __uint_as_float(smB[1]));
        if (!__all(pmA <= mA + 8.0f)) {
            float mn = fmaxf(mA, pmA);
            float sc = __builtin_exp2f(mA - mn);
            lA *= sc;
            #pragma unroll
            for (int r = 0; r < 16; ++r) { oA0[r] *= sc; oA1[r] *= sc; }
            mA = mn;
        }
        if (!__all(pmB <= mB + 8.0f)) {
            float mn = fmaxf(mB, pmB);
            float sc = __builtin_exp2f(mB - mn);
            lB *= sc;
            #pragma unroll
            for (int r = 0; r < 16; ++r) { oB0[r] *= sc; oB1[r] *= sc; }
            mB = mn;
        }
        #pragma unroll
        for (int r = 0; r < 16; ++r) {
            stA[r] = __builtin_exp2f(stA[r] - mA);
            stB[r] = __builtin_exp2f(stB[r] - mB);
        }
        float psA = vsum16(stA);
        float psB = vsum16(stB);
        u32x2 ssA = plswap(__float_as_uint(psA), __float_as_uint(psA));
        u32x2 ssB = plswap(__float_as_uint(psB), __float_as_uint(psB));
        lA += __uint_as_float(ssA[0]) + __uint_as_float(ssA[1]);
        lB += __uint_as_float(ssB[0]) + __uint_as_float(ssB[1]);

        // ---- P^T -> bf16 B-fragments (cvt_pk + permlane32_swap), both tiles ----
        bf16x8 bpA0, bpA1, bpB0, bpB1;
        {
            uint32_t u0 = pk2bf(stA[0],  stA[1]),  u1 = pk2bf(stA[2],  stA[3]);
            uint32_t u2 = pk2bf(stA[4],  stA[5]),  u3 = pk2bf(stA[6],  stA[7]);
            uint32_t u4 = pk2bf(stA[8],  stA[9]),  u5 = pk2bf(stA[10], stA[11]);
            uint32_t u6 = pk2bf(stA[12], stA[13]), u7 = pk2bf(stA[14], stA[15]);
            u32x2 sA = plswap(u0, u2), sB = plswap(u1, u3);
            bpA0 = mk8(sA[0], sB[0], sA[1], sB[1]);
            u32x2 sC = plswap(u4, u6), sD = plswap(u5, u7);
            bpA1 = mk8(sC[0], sD[0], sC[1], sD[1]);
        }
        {
            uint32_t u0 = pk2bf(stB[0],  stB[1]),  u1 = pk2bf(stB[2],  stB[3]);
            uint32_t u2 = pk2bf(stB[4],  stB[5]),  u3 = pk2bf(stB[6],  stB[7]);
            uint32_t u4 = pk2bf(stB[8],  stB[9]),  u5 = pk2bf(stB[10], stB[11]);
            uint32_t u6 = pk2bf(stB[12], stB[13]), u7 = pk2bf(stB[14], stB[15]);
            u32x2 sA = plswap(u0, u2), sB = plswap(u1, u3);
            bpB0 = mk8(sA[0], sB[0], sA[1], sB[1]);
            u32x2 sC = plswap(u4, u6), sD = plswap(u5, u7);
            bpB1 = mk8(sC[0], sD[0], sC[1], sD[1]);
        }

        // ---- O^T += V^T * P^T: 8 MFMAs, 4 independent accumulator chains ----
        oA0 = __builtin_amdgcn_mfma_f32_32x32x16_bf16(va[0], bpA0, oA0, 0, 0, 0);
        oB0 = __builtin_amdgcn_mfma_f32_32x32x16_bf16(va[0], bpB0, oB0, 0, 0, 0);
        oA1 = __builtin_amdgcn_mfma_f32_32x32x16_bf16(va[2], bpA0, oA1, 0, 0, 0);
        oB1 = __builtin_amdgcn_mfma_f32_32x32x16_bf16(va[2], bpB0, oB1, 0, 0, 0);
        oA0 = __builtin_amdgcn_mfma_f32_32x32x16_bf16(va[1], bpA1, oA0, 0, 0, 0);
        oB0 = __builtin_amdgcn_mfma_f32_32x32x16_bf16(va[1], bpB1, oB0, 0, 0, 0);
        oA1 = __builtin_amdgcn_mfma_f32_32x32x16_bf16(va[3], bpA1, oA1, 0, 0, 0);
        oB1 = __builtin_amdgcn_mfma_f32_32x32x16_bf16(va[3], bpB1, oB1, 0, 0, 0);

        #pragma unroll
        for (int i = 0; i < 4; ++i) { ka[i] = kan[i]; va[i] = van[i]; }
    }

    // ---- 4-way split merge through LDS ----
    if (split != 0) {
        float* base = comb[split - 1];
        #pragma unroll
        for (int r = 0; r < 16; ++r) {
            base[r * 64 + lane]        = oA0[r];
            base[(r + 16) * 64 + lane] = oA1[r];
            base[(r + 32) * 64 + lane] = oB0[r];
            base[(r + 48) * 64 + lane] = oB1[r];
        }
        base[4096 + lane]       = mA;
        base[4096 + 64 + lane]  = lA;
        base[4096 + 128 + lane] = mB;
        base[4096 + 192 + lane] = lB;
    }
    __syncthreads();
    if (split == 0) {
        float MA = mA, MB = mB;
        #pragma unroll
        for (int j = 0; j < NSPLIT - 1; ++j) {
            MA = fmaxf(MA, comb[j][4096 + lane]);
            MB = fmaxf(MB, comb[j][4096 + 128 + lane]);
        }
        float scA = __builtin_exp2f(mA - MA), ltA = lA * scA;
        float scB = __builtin_exp2f(mB - MB), ltB = lB * scB;
        #pragma unroll
        for (int r = 0; r < 16; ++r) {
            oA0[r] *= scA; oA1[r] *= scA;
            oB0[r] *= scB; oB1[r] *= scB;
        }
        #pragma unroll
        for (int j = 0; j < NSPLIT - 1; ++j) {
            float mjA = comb[j][4096 + lane];
            float ljA = comb[j][4096 + 64 + lane];
            float mjB = comb[j][4096 + 128 + lane];
            float ljB = comb[j][4096 + 192 + lane];
            float sjA = __builtin_exp2f(mjA - MA);
            float sjB = __builtin_exp2f(mjB - MB);
            ltA += ljA * sjA;
            ltB += ljB * sjB;
            #pragma unroll
            for (int r = 0; r < 16; ++r) {
                oA0[r] += sjA * comb[j][r * 64 + lane];
                oA1[r] += sjA * comb[j][(r + 16) * 64 + lane];
                oB0[r] += sjB * comb[j][(r + 32) * 64 + lane];
                oB1[r] += sjB * comb[j][(r + 48) * 64 + lane];
            }
        }
        float invA = 1.0f / ltA, invB = 1.0f / ltB;
        float* opA = O + bOff + (size_t)(qb + ln) * DIM;
        float* opB = O + bOff + (size_t)(qb + 32 + ln) * DIM;
        #pragma unroll
        for (int a = 0; a < 4; ++a) {
            float4 w;
            w.x = oA0[4*a+0] * invA; w.y = oA0[4*a+1] * invA;
            w.z = oA0[4*a+2] * invA; w.w = oA0[4*a+3] * invA;
            *(float4*)(opA + 8*a + 4*h) = w;            // d = (r&3)+8*(r>>2)+4h
            w.x = oA1[4*a+0] * invA; w.y = oA1[4*a+1] * invA;
            w.z = oA1[4*a+2] * invA; w.w = oA1[4*a+3] * invA;
            *(float4*)(opA + 32 + 8*a + 4*h) = w;       // tile d+32
            w.x = oB0[4*a+0] * invB; w.y = oB0[4*a+1] * invB;
            w.z = oB0[4*a+2] * invB; w.w = oB0[4*a+3] * invB;
            *(float4*)(opB + 8*a + 4*h) = w;
            w.x = oB1[4*a+0] * invB; w.y = oB1[4*a+1] * invB;
            w.z = oB1[4*a+2] * invB; w.w = oB1[4*a+3] * invB;
            *(float4*)(opB + 32 + 8*a + 4*h) = w;
        }
    }
}

// ---------------- fallback (round-3 LDS kernel) if ws too small ------------
__device__ __forceinline__ uint32_t swz(uint32_t row, uint32_t colByte) {
    return row * 128u + (colByte ^ ((row & 7u) << 4));
}
__device__ __forceinline__ bf16x8 lds8(const char* p) {
    union { uint4 q; bf16x8 v; } c;
    c.q = *(const uint4*)p;
    return c.v;
}

__global__ __launch_bounds__(256, 2) void attn_fallback(
        const float* __restrict__ Q, const float* __restrict__ K,
        const float* __restrict__ V, const int* __restrict__ VL,
        float* __restrict__ O)
{
    __shared__ unsigned short lds[2][2][64 * DIM];
    const int tid  = threadIdx.x;
    const int bid  = blockIdx.x;
    const int b    = bid & (BATCH - 1);
    const int qt   = bid >> 4;
    const int qb   = qt * 64;
    const int qhalf = (tid >> 6) & 1;
    const int split = tid >> 7;
    const int lane = tid & 63;
    const int h    = lane >> 5;
    const int ln   = lane & 31;
    const int ptid = tid & 127;

    const int valid  = VL[b];
    const int ntiles = (valid + 63) / 64;
    const int nit    = (ntiles + 1) / 2;

    const size_t bOff = (size_t)b * SEQ * DIM;
    const int qrow = qb + qhalf * 32 + ln;

    bf16x8 qf[4];
    {
        const float* qp = Q + bOff + (size_t)qrow * DIM;
        #pragma unroll
        for (int s = 0; s < 4; ++s) {
            int c0 = s * 16 + h * 8;
            float4 x = *(const float4*)(qp + c0);
            float4 y = *(const float4*)(qp + c0 + 4);
            qf[s] = mk8(pk2bf(x.x * QSCALE, x.y * QSCALE),
                        pk2bf(x.z * QSCALE, x.w * QSCALE),
                        pk2bf(y.x * QSCALE, y.y * QSCALE),
                        pk2bf(y.z * QSCALE, y.w * QSCALE));
        }
    }
    f32x16 o0, o1;
    #pragma unroll
    for (int r = 0; r < 16; ++r) { o0[r] = 0.0f; o1[r] = 0.0f; }
    float m_run = -1e30f, l_run = 0.0f;
    const float* Kb = K + bOff;
    const float* Vb = V + bOff;
    char* kls = (char*)lds[split][0];
    char* vls = (char*)lds[split][1];

    for (int it = 0; it < nit; ++it) {
        const int kt = it * 2 + split;
        const bool act = kt < ntiles;
        const int kb = kt * 64;
        if (act) {
            #pragma unroll
            for (int p = 0; p < 8; ++p) {
                int idx = p * 128 + ptid;
                int r = idx >> 4, c = (idx & 15) * 4;
                float4 kx = *(const float4*)(Kb + (size_t)(kb + r) * DIM + c);
                *(uint2*)(kls + swz(r, c * 2)) =
                    make_uint2(pk2bf(kx.x, kx.y), pk2bf(kx.z, kx.w));
            }
            #pragma unroll
            for (int p = 0; p < 2; ++p) {
                int idx = p * 128 + ptid;
                int cq = idx & 15, rq = idx >> 4;
                const float* vp = Vb + (size_t)(kb + rq * 4) * DIM + cq * 4;
                float4 v0 = *(const float4*)(vp);
                float4 v1 = *(const float4*)(vp + DIM);
                float4 v2 = *(const float4*)(vp + 2 * DIM);
                float4 v3 = *(const float4*)(vp + 3 * DIM);
                float a0[4] = {v0.x, v0.y, v0.z, v0.w};
                float a1[4] = {v1.x, v1.y, v1.z, v1.w};
                float a2[4] = {v2.x, v2.y, v2.z, v2.w};
                float a3[4] = {v3.x, v3.y, v3.z, v3.w};
                #pragma unroll
                for (int i = 0; i < 4; ++i)
                    *(uint2*)(vls + swz(cq * 4 + i, rq * 8)) =
                        make_uint2(pk2bf(a0[i], a1[i]), pk2bf(a2[i], a3[i]));
            }
        }
        __syncthreads();
        if (act) {
            f32x16 st0, st1;
            #pragma unroll
            for (int r = 0; r < 16; ++r) { st0[r] = 0.0f; st1[r] = 0.0f; }
            #pragma unroll
            for (int s = 0; s < 4; ++s) {
                int cb = (s * 16 + h * 8) * 2;
                bf16x8 ka0 = lds8(kls + swz(ln,      cb));
                bf16x8 ka1 = lds8(kls + swz(ln + 32, cb));
                st0 = __builtin_amdgcn_mfma_f32_32x32x16_bf16(ka0, qf[s], st0, 0, 0, 0);
                st1 = __builtin_amdgcn_mfma_f32_32x32x16_bf16(ka1, qf[s], st1, 0, 0, 0);
            }
            if (kb + 64 > valid) {
                #pragma unroll
                for (int r = 0; r < 16; ++r) {
                    int krel = (r & 3) + 8 * (r >> 2) + 4 * h;
                    if (kb + krel      >= valid) st0[r] = -1e30f;
                    if (kb + 32 + krel >= valid) st1[r] = -1e30f;
                }
            }
            float pm = fmaxf(vmax16(st0), vmax16(st1));
            u32x2 sm = plswap(__float_as_uint(pm), __float_as_uint(pm));
            pm = fmaxf(__uint_as_float(sm[0]), __uint_as_float(sm[1]));
            float mnew = fmaxf(m_run, pm);
            float sc = __builtin_exp2f(m_run - mnew);
            #pragma unroll
            for (int r = 0; r < 16; ++r) {
                st0[r] = __builtin_exp2f(st0[r] - mnew);
                st1[r] = __builtin_exp2f(st1[r] - mnew);
            }
            float ps = vsum16(st0) + vsum16(st1);
            u32x2 ss = plswap(__float_as_uint(ps), __float_as_uint(ps));
            ps = __uint_as_float(ss[0]) + __uint_as_float(ss[1]);
            l_run = l_run * sc + ps;
            m_run = mnew;
            #pragma unroll
            for (int r = 0; r < 16; ++r) { o0[r] *= sc; o1[r] *= sc; }
            bf16x8 bp[4];
            {
                uint32_t u0 = pk2bf(st0[0], st0[1]),  u1 = pk2bf(st0[2], st0[3]);
                uint32_t u2 = pk2bf(st0[4], st0[5]),  u3 = pk2bf(st0[6], st0[7]);
                uint32_t u4 = pk2bf(st0[8], st0[9]),  u5 = pk2bf(st0[10], st0[11]);
                uint32_t u6 = pk2bf(st0[12], st0[13]), u7 = pk2bf(st0[14], st0[15]);
                u32x2 s02 = plswap(u0, u2), s13 = plswap(u1, u3);
                bp[0] = mk8(s02[0], s13[0], s02[1], s13[1]);
                u32x2 s46 = plswap(u4, u6), s57 = plswap(u5, u7);
                bp[1] = mk8(s46[0], s57[0], s46[1], s57[1]);
            }
            {
                uint32_t u0 = pk2bf(st1[0], st1[1]),  u1 = pk2bf(st1[2], st1[3]);
                uint32_t u2 = pk2bf(st1[4], st1[5]),  u3 = pk2bf(st1[6], st1[7]);
                uint32_t u4 = pk2bf(st1[8], st1[9]),  u5 = pk2bf(st1[10], st1[11]);
                uint32_t u6 = pk2bf(st1[12], st1[13]), u7 = pk2bf(st1[14], st1[15]);
                u32x2 s02 = plswap(u0, u2), s13 = plswap(u1, u3);
                bp[2] = mk8(s02[0], s13[0], s02[1], s13[1]);
                u32x2 s46 = plswap(u4, u6), s57 = plswap(u5, u7);
                bp[3] = mk8(s46[0], s57[0], s46[1], s57[1]);
            }
            #pragma unroll
            for (int x = 0; x < 4; ++x) {
                int cb = (x * 16 + h * 8) * 2;
                bf16x8 va0 = lds8(vls + swz(ln,      cb));
                bf16x8 va1 = lds8(vls + swz(ln + 32, cb));
                o0 = __builtin_amdgcn_mfma_f32_32x32x16_bf16(va0, bp[x], o0, 0, 0, 0);
                o1 = __builtin_amdgcn_mfma_f32_32x32x16_bf16(va1, bp[x], o1, 0, 0, 0);
            }
        }
        __syncthreads();
    }
    const int CSTRIDE = 32 * 64 + 128;
    float* comb = (float*)lds;
    if (split != 0) {
        float* base = comb + (size_t)qhalf * CSTRIDE;
        #pragma unroll
        for (int r = 0; r < 16; ++r) {
            base[r * 64 + lane]        = o0[r];
            base[(r + 16) * 64 + lane] = o1[r];
        }
        base[2048 + lane]      = m_run;
        base[2048 + 64 + lane] = l_run;
    }
    __syncthreads();
    if (split == 0) {
        float* base = comb + (size_t)qhalf * CSTRIDE;
        float mj = base[2048 + lane];
        float lj = base[2048 + 64 + lane];
        float M  = fmaxf(m_run, mj);
        float sc0 = __builtin_exp2f(m_run - M);
        float scj = __builtin_exp2f(mj - M);
        float lt = l_run * sc0 + lj * scj;
        float inv = 1.0f / lt;
        float* op = O + bOff + (size_t)qrow * DIM;
        #pragma unroll
        for (int a = 0; a < 4; ++a) {
            float4 w0, w1;
            w0.x = (o0[4*a+0]*sc0 + scj*base[(4*a+0)*64 + lane]) * inv;
            w0.y = (o0[4*a+1]*sc0 + scj*base[(4*a+1)*64 + lane]) * inv;
            w0.z = (o0[4*a+2]*sc0 + scj*base[(4*a+2)*64 + lane]) * inv;
            w0.w = (o0[4*a+3]*sc0 + scj*base[(4*a+3)*64 + lane]) * inv;
            w1.x = (o1[4*a+0]*sc0 + scj*base[(4*a+16)*64 + lane]) * inv;
            w1.y = (o1[4*a+1]*sc0 + scj*base[(4*a+17)*64 + lane]) * inv;
            w1.z = (o1[4*a+2]*sc0 + scj*base[(4*a+18)*64 + lane]) * inv;
            w1.w = (o1[4*a+3]*sc0 + scj*base[(4*a+19)*64 + lane]) * inv;
            *(float4*)(op + 8*a + 4*h)      = w0;
            *(float4*)(op + 32 + 8*a + 4*h) = w1;
        }
    }
}

extern "C" void kernel_launch(void* const* d_in, const int* in_sizes, int n_in,
                              void* d_out, int out_size, void* d_ws, size_t ws_size,
                              hipStream_t stream) {
    const float* q  = (const float*)d_in[0];
    const float* k  = (const float*)d_in[1];
    const float* v  = (const float*)d_in[2];
    const int*   vl = (const int*)d_in[3];
    float* out = (float*)d_out;

    const size_t KBYTES = (size_t)BATCH * SEQ * DIM * 2;   // 4 MB each
    if (ws_size >= 2 * KBYTES) {
        unsigned short* kws = (unsigned short*)d_ws;
        unsigned short* vws = (unsigned short*)((char*)d_ws + KBYTES);
        hipLaunchKernelGGL(prep_kv, dim3(BATCH * (SEQ / 64)), dim3(256), 0, stream,
                           k, v, kws, vws);
        hipLaunchKernelGGL(attn_main, dim3(BATCH * (SEQ / 64)), dim3(NTHR), 0, stream,
                           q, kws, vws, vl, out);
    } else {
        hipLaunchKernelGGL(attn_fallback, dim3(BATCH * (SEQ / 64)), dim3(256), 0, stream,
                           q, k, v, vl, out);
    }
}